// Round 1
// baseline (162.037 us; speedup 1.0000x reference)
//
#include <hip/hip_runtime.h>

// Problem constants (reference: B=32, N=128, D=64; B derived at launch).
#define N_TOK 128
#define DIM   64
#define LN_EPS 1e-5f
#define SLOPE  0.01f

__device__ __forceinline__ float wave_reduce_sum(float v) {
#pragma unroll
    for (int off = 32; off >= 1; off >>= 1) v += __shfl_xor(v, off, 64);
    return v;
}
__device__ __forceinline__ float wave_reduce_max(float v) {
#pragma unroll
    for (int off = 32; off >= 1; off >>= 1) v = fmaxf(v, __shfl_xor(v, off, 64));
    return v;
}

// ---------------------------------------------------------------------------
// K0: per-row LayerNorm stats -> q_score[b,n], k_score[b,n]
//   q = rsq*(dot(e, g*wq) - mu*S_gwq) + S_bwq   (LN folded algebraically)
// One wave per row, lane = d. 4 row reductions + 4 weight reductions.
// ---------------------------------------------------------------------------
__global__ __launch_bounds__(256) void k0_row_stats(
        const float* __restrict__ emb, const float* __restrict__ gamma,
        const float* __restrict__ beta, const float* __restrict__ attw,
        float* __restrict__ q_ws, float* __restrict__ k_ws, int nrows) {
    int wave = threadIdx.x >> 6, lane = threadIdx.x & 63;
    int r = blockIdx.x * 4 + wave;
    if (r >= nrows) return;
    float e  = emb[r * DIM + lane];
    float g  = gamma[lane], bt = beta[lane];
    float wq = attw[lane], wk = attw[DIM + lane];
    float gwq = g * wq, gwk = g * wk;

    float se  = wave_reduce_sum(e);
    float se2 = wave_reduce_sum(e * e);
    float sq  = wave_reduce_sum(e * gwq);
    float sk  = wave_reduce_sum(e * gwk);
    float Sgq = wave_reduce_sum(gwq);
    float Sbq = wave_reduce_sum(bt * wq);
    float Sgk = wave_reduce_sum(gwk);
    float Sbk = wave_reduce_sum(bt * wk);

    if (lane == 0) {
        float mu  = se * (1.f / 64.f);
        float var = se2 * (1.f / 64.f) - mu * mu;
        float rsq = rsqrtf(var + LN_EPS);
        q_ws[r] = rsq * (sq - mu * Sgq) + Sbq;
        k_ws[r] = rsq * (sk - mu * Sgk) + Sbk;
    }
}

// ---------------------------------------------------------------------------
// K1: scores + leaky + softmax -> alphas.
// Block = 256 threads, handles (b, i0) and (b, i0+1). e[b] staged transposed
// [d][j] in LDS with XOR swizzle (j ^ (d&31)) -> all reads 2-way (free).
// Each lane owns one j and serially accumulates 3 dots over d (no cross-lane
// reduction in hot loop):
//   s1 = dot(e_i,e_j), s2 = dot((e_i*e_j)^2), s3 = dot(e_i*g*wv, e_j)
// ---------------------------------------------------------------------------
__global__ __launch_bounds__(256) void k1_scores(
        const float* __restrict__ emb, const float* __restrict__ gamma,
        const float* __restrict__ beta, const float* __restrict__ attw,
        const float* __restrict__ attb, const float* __restrict__ q_ws,
        const float* __restrict__ k_ws, float* __restrict__ alphas) {
    __shared__ float e_tr[DIM * N_TOK];   // [d][j^ (d&31)]  32 KB
    __shared__ float EV[2][DIM];          // e_i * gamma * wv
    __shared__ float sc_lds[2][N_TOK];
    __shared__ float S[3];                // S_gwv, S_bwv, att_b

    int b  = blockIdx.x >> 6;
    int i0 = (blockIdx.x & 63) * 2;

    // --- stage e[b] transposed+swizzled ---
    const float4* E4 = (const float4*)(emb + (size_t)b * (N_TOK * DIM));
#pragma unroll
    for (int l = 0; l < 8; ++l) {
        int idx4 = l * 256 + threadIdx.x;        // [0, 2048)
        int j = idx4 >> 4, c = idx4 & 15;
        float4 v = E4[idx4];
        int d0 = c * 4;
        e_tr[(d0 + 0) * N_TOK + (j ^ ((d0 + 0) & 31))] = v.x;
        e_tr[(d0 + 1) * N_TOK + (j ^ ((d0 + 1) & 31))] = v.y;
        e_tr[(d0 + 2) * N_TOK + (j ^ ((d0 + 2) & 31))] = v.z;
        e_tr[(d0 + 3) * N_TOK + (j ^ ((d0 + 3) & 31))] = v.w;
    }
    __syncthreads();

    // --- weight scalars (wave 0) and EV precompute (threads 128..255) ---
    if (threadIdx.x < 64) {
        int d = threadIdx.x;
        float g = gamma[d], bt = beta[d], wv = attw[2 * DIM + d];
        float sg = wave_reduce_sum(g * wv);
        float sb = wave_reduce_sum(bt * wv);
        if (d == 0) { S[0] = sg; S[1] = sb; S[2] = attb[0]; }
    } else if (threadIdx.x >= 128) {
        int t2 = threadIdx.x - 128;
        int il = t2 >> 6, d = t2 & 63;
        int i = i0 + il;
        float ei = e_tr[d * N_TOK + (i ^ (d & 31))];
        EV[il][d] = ei * gamma[d] * attw[2 * DIM + d];
    }
    __syncthreads();

    // --- score loop: wave w -> (i0 + w/2, j-half w&1), lane owns one j ---
    int w = threadIdx.x >> 6, lane = threadIdx.x & 63;
    int il = w >> 1, i = i0 + il;
    int j  = ((w & 1) << 6) | lane;
    float qi = q_ws[b * N_TOK + i];
    float kj = k_ws[b * N_TOK + j];
    float s1 = 0.f, s2 = 0.f, s3 = 0.f;
#pragma unroll
    for (int d = 0; d < DIM; ++d) {
        float ej = e_tr[d * N_TOK + (j ^ (d & 31))];   // per-lane, 2-way free
        float pi = e_tr[d * N_TOK + (i ^ (d & 31))];   // uniform -> broadcast
        float t  = pi * ej;
        s1 += t;
        s2 = fmaf(t, t, s2);
        s3 = fmaf(EV[il][d], ej, s3);                  // uniform -> broadcast
    }
    float mu  = s1 * (1.f / 64.f);
    float var = s2 * (1.f / 64.f) - mu * mu;
    float rsq = rsqrtf(var + LN_EPS);
    float vsc = rsq * (s3 - mu * S[0]) + S[1];
    float sc  = qi + kj + vsc + S[2];
    sc = sc >= 0.f ? sc : SLOPE * sc;                  // leaky relu
    sc_lds[il][j] = sc;
    __syncthreads();

    // --- softmax over j (128) : waves 0,1 handle i0, i0+1 ---
    if (w < 2) {
        float a  = sc_lds[w][lane];
        float bb = sc_lds[w][lane + 64];
        float m  = wave_reduce_max(fmaxf(a, bb));
        float ea = __expf(a - m), eb = __expf(bb - m);
        float s  = wave_reduce_sum(ea + eb);
        float inv = 1.f / s;
        float* arow = alphas + ((size_t)(b * N_TOK + i0 + w)) * N_TOK;
        arow[lane]      = ea * inv;
        arow[lane + 64] = eb * inv;
    }
}

// ---------------------------------------------------------------------------
// K2: value[b,i,j,d] = e[b,i,d] * e[b,j,d]. Pure streaming, float4 I/O.
// 128 MiB of writes -> this is the HBM floor of the whole problem.
// ---------------------------------------------------------------------------
__global__ __launch_bounds__(256) void k2_value(
        const float* __restrict__ emb, float4* __restrict__ out4, int total4) {
    const float4* E4 = (const float4*)emb;
    int tid = blockIdx.x * 256 + threadIdx.x;
    int stride = gridDim.x * 256;
    for (int idx4 = tid; idx4 < total4; idx4 += stride) {
        int c = idx4 & 15;                 // d/4
        int j = (idx4 >> 4) & 127;
        int i = (idx4 >> 11) & 127;
        int b = idx4 >> 18;
        float4 a = E4[(((b << 7) | i) << 4) | c];   // L1/L2-hot (1 MiB total)
        float4 e = E4[(((b << 7) | j) << 4) | c];
        float4 v;
        v.x = a.x * e.x; v.y = a.y * e.y; v.z = a.z * e.z; v.w = a.w * e.w;
        out4[idx4] = v;                    // coalesced dwordx4
    }
}

extern "C" void kernel_launch(void* const* d_in, const int* in_sizes, int n_in,
                              void* d_out, int out_size, void* d_ws, size_t ws_size,
                              hipStream_t stream) {
    const float* emb   = (const float*)d_in[0];
    const float* gamma = (const float*)d_in[1];
    const float* beta  = (const float*)d_in[2];
    const float* attw  = (const float*)d_in[3];
    const float* attb  = (const float*)d_in[4];
    float* out = (float*)d_out;

    int B = in_sizes[0] / (N_TOK * DIM);     // 32
    int nrows = B * N_TOK;                   // 4096
    float* q_ws = (float*)d_ws;
    float* k_ws = q_ws + nrows;

    float* alphas = out;                             // B*N*N floats
    float* value  = out + (size_t)nrows * N_TOK;     // B*N*N*D floats
    int total4 = B * N_TOK * N_TOK * (DIM / 4);      // 8,388,608

    k0_row_stats<<<dim3((nrows + 3) / 4), dim3(256), 0, stream>>>(
        emb, gamma, beta, attw, q_ws, k_ws, nrows);
    k1_scores<<<dim3(B * 64), dim3(256), 0, stream>>>(
        emb, gamma, beta, attw, attb, q_ws, k_ws, alphas);
    k2_value<<<dim3(B * 128), dim3(256), 0, stream>>>(
        emb, (float4*)value, total4);
}

// Round 4
// 151.258 us; speedup vs baseline: 1.0713x; 1.0713x over previous
//
#include <hip/hip_runtime.h>

#define N_TOK 128
#define DIM   64
#define LN_EPS 1e-5f
#define SLOPE  0.01f

__device__ __forceinline__ float wave_reduce_sum(float v) {
#pragma unroll
    for (int off = 32; off >= 1; off >>= 1) v += __shfl_xor(v, off, 64);
    return v;
}
__device__ __forceinline__ float wave_reduce_max(float v) {
#pragma unroll
    for (int off = 32; off >= 1; off >>= 1) v = fmaxf(v, __shfl_xor(v, off, 64));
    return v;
}

// ---------------------------------------------------------------------------
// K0: per-row LayerNorm stats -> q_score[b,n], k_score[b,n]  (LN folded)
// One wave per row, lane = d.
// ---------------------------------------------------------------------------
__global__ __launch_bounds__(256) void k0_row_stats(
        const float* __restrict__ emb, const float* __restrict__ gamma,
        const float* __restrict__ beta, const float* __restrict__ attw,
        float* __restrict__ q_ws, float* __restrict__ k_ws, int nrows) {
    int wave = threadIdx.x >> 6, lane = threadIdx.x & 63;
    int r = blockIdx.x * 4 + wave;
    if (r >= nrows) return;
    float e  = emb[r * DIM + lane];
    float g  = gamma[lane], bt = beta[lane];
    float wq = attw[lane], wk = attw[DIM + lane];
    float gwq = g * wq, gwk = g * wk;

    float se  = wave_reduce_sum(e);
    float se2 = wave_reduce_sum(e * e);
    float sq  = wave_reduce_sum(e * gwq);
    float sk  = wave_reduce_sum(e * gwk);
    float Sgq = wave_reduce_sum(gwq);
    float Sbq = wave_reduce_sum(bt * wq);
    float Sgk = wave_reduce_sum(gwk);
    float Sbk = wave_reduce_sum(bt * wk);

    if (lane == 0) {
        float mu  = se * (1.f / 64.f);
        float var = se2 * (1.f / 64.f) - mu * mu;
        float rsq = rsqrtf(var + LN_EPS);
        q_ws[r] = rsq * (sq - mu * Sgq) + Sbq;
        k_ws[r] = rsq * (sk - mu * Sgk) + Sbk;
    }
}

// ---------------------------------------------------------------------------
// K12 (fused): one block per (b,i). Computes value[b,i,:,:] (the 32 KB row,
// streamed out as float4) AND reuses the same products t4 = e_i*e_j in
// registers for the three score dot-products:
//   s1 = dot(e_i,e_j)   s2 = dot(t,t)   s3 = dot(t, gamma*wv)
// 16-lane group owns one j (c = lane&15 covers d in float4 chunks); the 3
// sums reduce with 4 shfl_xor steps inside the group. Then leaky+softmax.
// Score math hides under the 32 KB/block store drain (HBM-write-bound).
// ---------------------------------------------------------------------------
__global__ __launch_bounds__(256) void k12_fused(
        const float* __restrict__ emb, const float* __restrict__ gamma,
        const float* __restrict__ beta, const float* __restrict__ attw,
        const float* __restrict__ attb, const float* __restrict__ q_ws,
        const float* __restrict__ k_ws, float* __restrict__ alphas,
        float4* __restrict__ value4) {
    __shared__ float sc_lds[N_TOK];

    int b = blockIdx.x >> 7;
    int i = blockIdx.x & 127;
    int c  = threadIdx.x & 15;     // float4 chunk over d
    int jg = threadIdx.x >> 4;     // j-group 0..15

    const float4* E4 = (const float4*)emb + ((size_t)(b * N_TOK) << 4);
    float4 a4  = E4[(i << 4) | c];                         // e_i chunk
    float4 g4  = ((const float4*)gamma)[c];
    float4 bt4 = ((const float4*)beta)[c];
    float4 wv4 = ((const float4*)(attw + 2 * DIM))[c];
    float gwx = g4.x * wv4.x, gwy = g4.y * wv4.y,
          gwz = g4.z * wv4.z, gww = g4.w * wv4.w;

    // group-wide scalars: Sg = sum(gamma*wv), Sb = sum(beta*wv)
    float Sg = gwx + gwy + gwz + gww;
    float Sb = bt4.x * wv4.x + bt4.y * wv4.y + bt4.z * wv4.z + bt4.w * wv4.w;
#pragma unroll
    for (int off = 1; off < 16; off <<= 1) {
        Sg += __shfl_xor(Sg, off);
        Sb += __shfl_xor(Sb, off);
    }
    float qi = q_ws[b * N_TOK + i] + attb[0];

    float4* vrow = value4 + ((size_t)blockIdx.x << 11);    // 2048 float4 / row

#pragma unroll
    for (int it = 0; it < 8; ++it) {
        int j = (it << 4) | jg;
        float4 e4 = E4[(j << 4) | c];                      // L1/L2-hot
        float4 t4;
        t4.x = a4.x * e4.x; t4.y = a4.y * e4.y;
        t4.z = a4.z * e4.z; t4.w = a4.w * e4.w;
        vrow[(j << 4) | c] = t4;                           // coalesced dwordx4

        float s1 = t4.x + t4.y + t4.z + t4.w;
        float s2 = t4.x * t4.x + t4.y * t4.y + t4.z * t4.z + t4.w * t4.w;
        float s3 = t4.x * gwx + t4.y * gwy + t4.z * gwz + t4.w * gww;
#pragma unroll
        for (int off = 1; off < 16; off <<= 1) {
            s1 += __shfl_xor(s1, off);
            s2 += __shfl_xor(s2, off);
            s3 += __shfl_xor(s3, off);
        }
        if (c == 0) {
            float mu  = s1 * (1.f / 64.f);
            float var = s2 * (1.f / 64.f) - mu * mu;
            float rsq = rsqrtf(var + LN_EPS);
            float vsc = rsq * (s3 - mu * Sg) + Sb;
            float sc  = qi + k_ws[b * N_TOK + j] + vsc;
            sc_lds[j] = sc >= 0.f ? sc : SLOPE * sc;       // leaky relu
        }
    }
    __syncthreads();

    // softmax over 128 scores: wave 0 only
    if (threadIdx.x < 64) {
        int lane = threadIdx.x;
        float va = sc_lds[lane];
        float vb = sc_lds[lane + 64];
        float m  = wave_reduce_max(fmaxf(va, vb));
        float ea = __expf(va - m), eb = __expf(vb - m);
        float s  = wave_reduce_sum(ea + eb);
        float inv = 1.f / s;
        float* arow = alphas + ((size_t)blockIdx.x << 7);
        arow[lane]      = ea * inv;
        arow[lane + 64] = eb * inv;
    }
}

extern "C" void kernel_launch(void* const* d_in, const int* in_sizes, int n_in,
                              void* d_out, int out_size, void* d_ws, size_t ws_size,
                              hipStream_t stream) {
    const float* emb   = (const float*)d_in[0];
    const float* gamma = (const float*)d_in[1];
    const float* beta  = (const float*)d_in[2];
    const float* attw  = (const float*)d_in[3];
    const float* attb  = (const float*)d_in[4];
    float* out = (float*)d_out;

    int B = in_sizes[0] / (N_TOK * DIM);     // 32
    int nrows = B * N_TOK;                   // 4096
    float* q_ws = (float*)d_ws;
    float* k_ws = q_ws + nrows;

    float* alphas = out;                             // B*N*N floats
    float* value  = out + (size_t)nrows * N_TOK;     // B*N*N*D floats

    k0_row_stats<<<dim3((nrows + 3) / 4), dim3(256), 0, stream>>>(
        emb, gamma, beta, attw, q_ws, k_ws, nrows);
    k12_fused<<<dim3(nrows), dim3(256), 0, stream>>>(
        emb, gamma, beta, attw, attb, q_ws, k_ws, alphas, (float4*)value);
}